// Round 7
// baseline (317.028 us; speedup 1.0000x reference)
//
#include <hip/hip_runtime.h>
#include <math.h>

// Problem constants (from setup_inputs)
#define NN 100000            // nodes
#define NE 1600000           // real edges
#define ET (NE + NN)         // edges + self loops = 1,700,000
#define FIN 128
#define H1 4
#define C1 8
#define F1 32                // H1*C1
#define FOUT 16
#define NSLOPE 0.2f

// Radix-partition parameters (CSR build)
#define PARTW 256                          // nodes per dst-partition
#define PSHIFT 8
#define NPART ((NN + PARTW - 1) / PARTW)   // 391
#define CHUNK 8192                         // edges per hist/part block
#define NBLK ((ET + CHUNK - 1) / CHUNK)    // 208
#define CPAD 16                            // ints: 1 global counter per 64B line

typedef _Float16 half8 __attribute__((ext_vector_type(8)));

// ---------------- scan helpers ----------------

__device__ inline int wave_incl_scan(int v) {
#pragma unroll
    for (int off = 1; off < 64; off <<= 1) {
        int u = __shfl_up(v, off);
        if ((threadIdx.x & 63) >= off) v += u;
    }
    return v;
}

__device__ inline int block_excl_scan(int v, int* wsum, int nw) {
    int t = threadIdx.x, wid = t >> 6, lane = t & 63;
    int incl = wave_incl_scan(v);
    if (lane == 63) wsum[wid] = incl;
    __syncthreads();
    if (wid == 0) {
        int wv = (lane < nw) ? wsum[lane] : 0;
        wv = wave_incl_scan(wv);
        if (lane < nw) wsum[lane] = wv;
    }
    __syncthreads();
    return incl - v + (wid ? wsum[wid - 1] : 0);
}

// ---------------- CSR build ----------------

// Pass 1: LDS histogram -> one global atomicAdd per (block,partition).
// ptotal padded to 1 counter per 64B line: contention spread over 391 lines.
__global__ __launch_bounds__(1024) void k_hist(const int* __restrict__ dstA, int* __restrict__ ptotal) {
    __shared__ int h[NPART];
    int t = threadIdx.x;
    for (int i = t; i < NPART; i += 1024) h[i] = 0;
    __syncthreads();
    int base = blockIdx.x * CHUNK;
#pragma unroll
    for (int k = 0; k < CHUNK / 1024; k++) {
        int e = base + k * 1024 + t;
        if (e < ET) {
            int d = (e < NE) ? dstA[e] : (e - NE);   // virtual self-loop edges
            atomicAdd(&h[d >> PSHIFT], 1);
        }
    }
    __syncthreads();
    for (int i = t; i < NPART; i += 1024)
        if (h[i]) atomicAdd(&ptotal[i * CPAD], h[i]);
}

// Pass 2: scan 391 partition totals (1 block) -> pbase, init gcur.
__global__ __launch_bounds__(512) void k_pbase(const int* __restrict__ ptotal, int* __restrict__ pbase,
                                               int* __restrict__ gcur, int* __restrict__ rowstart) {
    __shared__ int wsum[8];
    int t = threadIdx.x;
    int v = (t < NPART) ? ptotal[t * CPAD] : 0;
    int excl = block_excl_scan(v, wsum, 8);
    if (t < NPART) { pbase[t] = excl; gcur[t * CPAD] = excl; }
    if (t == 0) { pbase[NPART] = ET; rowstart[NN] = ET; }
}

// Pass 3: LDS hist + global range-reserve per (block,partition) + scatter
// packed (dloc<<17)|src into partition-ordered pairs buffer.
__global__ __launch_bounds__(1024) void k_part(const int* __restrict__ srcA, const int* __restrict__ dstA,
                                               int* __restrict__ gcur, int* __restrict__ pairs) {
    __shared__ int h[NPART];
    __shared__ int cur[NPART];
    int t = threadIdx.x;
    for (int i = t; i < NPART; i += 1024) h[i] = 0;
    __syncthreads();
    int base = blockIdx.x * CHUNK;
#pragma unroll
    for (int k = 0; k < CHUNK / 1024; k++) {
        int e = base + k * 1024 + t;
        if (e < ET) {
            int d = (e < NE) ? dstA[e] : (e - NE);
            atomicAdd(&h[d >> PSHIFT], 1);
        }
    }
    __syncthreads();
    for (int i = t; i < NPART; i += 1024) {
        int c = h[i];
        cur[i] = c ? atomicAdd(&gcur[i * CPAD], c) : 0;   // reserve contiguous range
    }
    __syncthreads();
#pragma unroll
    for (int k = 0; k < CHUNK / 1024; k++) {
        int e = base + k * 1024 + t;
        if (e < ET) {
            int s, d;
            if (e < NE) { s = srcA[e]; d = dstA[e]; }
            else        { s = e - NE;  d = s; }
            int pos = atomicAdd(&cur[d >> PSHIFT], 1);    // LDS atomic
            pairs[pos] = ((d & (PARTW - 1)) << 17) | s;   // src < 2^17, dloc < 2^8
        }
    }
}

// Pass 4: per-partition counting sort (emits rowstart + esrc) FUSED with the
// per-(edge,head) attention weight: ew[h*ET+pos] = exp(leakyrelu(as1[s,h]+ad1[d,h])).
// Needs as1/ad1 -> runs after k_gemm1.
__global__ __launch_bounds__(1024) void k_sort(const int* __restrict__ pbase, const int* __restrict__ pairs,
                                               const float* __restrict__ as1, const float* __restrict__ ad1,
                                               int* __restrict__ rowstart, int* __restrict__ esrc,
                                               _Float16* __restrict__ ew) {
    __shared__ int hist[PARTW];
    __shared__ int sa[PARTW], sb[PARTW];
    int p = blockIdx.x;
    int t = threadIdx.x;
    int n0 = p << PSHIFT;
    int nn = min(PARTW, NN - n0);
    int base = pbase[p];
    int cnt = pbase[p + 1] - base;
    if (t < PARTW) hist[t] = 0;
    __syncthreads();
    for (int i = t; i < cnt; i += 1024)
        atomicAdd(&hist[pairs[base + i] >> 17], 1);
    __syncthreads();
    if (t < PARTW) sa[t] = hist[t];
    __syncthreads();
    int* pin = sa; int* pout = sb;
    for (int off = 1; off < PARTW; off <<= 1) {
        if (t < PARTW) pout[t] = pin[t] + ((t >= off) ? pin[t - off] : 0);
        __syncthreads();
        int* tmp = pin; pin = pout; pout = tmp;
    }
    int excl = 0;
    if (t < PARTW) {
        excl = pin[t] - hist[t];
        if (t < nn) rowstart[n0 + t] = base + excl;
    }
    __syncthreads();
    if (t < PARTW) hist[t] = excl;   // reuse as cursor
    __syncthreads();
    const float4* as4 = (const float4*)as1;
    const float4* ad4 = (const float4*)ad1;
    for (int i = t; i < cnt; i += 1024) {
        int v = pairs[base + i];
        int s = v & 0x1FFFF;
        int dl = v >> 17;
        int pos = base + atomicAdd(&hist[dl], 1);  // LDS atomic
        esrc[pos] = s;
        float4 as = as4[s];
        float4 ad = ad4[n0 + dl];
        float e0 = as.x + ad.x, e1 = as.y + ad.y, e2 = as.z + ad.z, e3 = as.w + ad.w;
        e0 = (e0 > 0.f) ? e0 : NSLOPE * e0;
        e1 = (e1 > 0.f) ? e1 : NSLOPE * e1;
        e2 = (e2 > 0.f) ? e2 : NSLOPE * e2;
        e3 = (e3 > 0.f) ? e3 : NSLOPE * e3;
        ew[0 * ET + pos] = (_Float16)__expf(e0);   // head planes: gather1 reads
        ew[1 * ET + pos] = (_Float16)__expf(e1);   // ew[h*ET+i] contiguously
        ew[2 * ET + pos] = (_Float16)__expf(e2);
        ew[3 * ET + pos] = (_Float16)__expf(e3);
    }
}

// ---------------- Layer 1: x@W1 + attention coefficients (xw1 stored fp16) ----------------

__global__ __launch_bounds__(256) void k_gemm1(const float* __restrict__ x, const float* __restrict__ W1,
        const float* __restrict__ a1s, const float* __restrict__ a1d,
        _Float16* __restrict__ xw1h, float* __restrict__ as1, float* __restrict__ ad1) {
    int n = blockIdx.x * 256 + threadIdx.x;
    if (n >= NN) return;
    float acc[F1];
#pragma unroll
    for (int c = 0; c < F1; c++) acc[c] = 0.f;
    const float4* x4 = (const float4*)(x + (size_t)n * FIN);
#pragma unroll 4
    for (int k4 = 0; k4 < FIN / 4; k4++) {
        float4 xv = x4[k4];
        float xk[4] = {xv.x, xv.y, xv.z, xv.w};
#pragma unroll
        for (int kk = 0; kk < 4; kk++) {
            int k = k4 * 4 + kk;
#pragma unroll
            for (int c = 0; c < F1; c++)
                acc[c] = fmaf(xk[kk], W1[k * F1 + c], acc[c]);  // W1 addr wave-uniform -> s_load
        }
    }
    half8* o8 = (half8*)(xw1h + (size_t)n * F1);
#pragma unroll
    for (int c8 = 0; c8 < F1 / 8; c8++) {
        half8 o;
#pragma unroll
        for (int k = 0; k < 8; k++) o[k] = (_Float16)acc[c8 * 8 + k];
        o8[c8] = o;
    }
#pragma unroll
    for (int h = 0; h < H1; h++) {
        float ss = 0.f, dd = 0.f;
#pragma unroll
        for (int c = 0; c < C1; c++) {
            ss = fmaf(acc[h*C1+c], a1s[h*C1+c], ss);
            dd = fmaf(acc[h*C1+c], a1d[h*C1+c], dd);
        }
        as1[n*H1+h] = ss;
        ad1[n*H1+h] = dd;
    }
}

// ---------------- Layer 1 gather: weighted aggregate + bias + ELU -> h1 (fp16) ----------------
// 64 lanes per node; halves process interleaved edges, unroll x4. Attention
// weights precomputed (ew planes) -> loop is pure load/fma, no exp.

__global__ __launch_bounds__(256) void k_gather1(const int* __restrict__ rowstart, const int* __restrict__ esrc,
        const _Float16* __restrict__ ew, const _Float16* __restrict__ xw1h,
        const float* __restrict__ b1, _Float16* __restrict__ h1h) {
    int n = blockIdx.x * 4 + (threadIdx.x >> 6);
    if (n >= NN) return;
    int l = threadIdx.x & 63;
    int c = l & 31;
    int h = c >> 3;
    int half = l >> 5;
    const _Float16* ewp = ew + (size_t)h * ET;   // this lane's head plane
    int beg = rowstart[n], end = rowstart[n + 1];
    float accn = 0.f, accd = 0.f;
    int i = beg + half;
    for (; i + 6 < end; i += 8) {
        int s0 = esrc[i], s1 = esrc[i + 2], s2 = esrc[i + 4], s3 = esrc[i + 6];
        float w0 = (float)ewp[i];
        float w1 = (float)ewp[i + 2];
        float w2 = (float)ewp[i + 4];
        float w3 = (float)ewp[i + 6];
        float x0 = (float)xw1h[s0 * F1 + c];
        float x1 = (float)xw1h[s1 * F1 + c];
        float x2 = (float)xw1h[s2 * F1 + c];
        float x3 = (float)xw1h[s3 * F1 + c];
        accd += (w0 + w1) + (w2 + w3);
        accn = fmaf(w0, x0, fmaf(w1, x1, fmaf(w2, x2, fmaf(w3, x3, accn))));
    }
    for (; i < end; i += 2) {
        int s0 = esrc[i];
        float w0 = (float)ewp[i];
        float x0 = (float)xw1h[s0 * F1 + c];
        accd += w0;
        accn = fmaf(w0, x0, accn);
    }
    accn += __shfl_xor(accn, 32);
    accd += __shfl_xor(accd, 32);
    float y = accn / accd + b1[c];
    y = (y > 0.f) ? y : expm1f(y);   // ELU
    if (l < 32) h1h[(size_t)n * F1 + c] = (_Float16)y;
}

// ---------------- Layer 2 node transform: h1@W2 + attention coefficients ----------------

__global__ __launch_bounds__(256) void k_node2(const _Float16* __restrict__ h1h, const float* __restrict__ W2,
        const float* __restrict__ a2s, const float* __restrict__ a2d,
        _Float16* __restrict__ xw2h, float* __restrict__ as2, float* __restrict__ ad2) {
    int n = blockIdx.x * 256 + threadIdx.x;
    if (n >= NN) return;
    float acc[FOUT];
#pragma unroll
    for (int j = 0; j < FOUT; j++) acc[j] = 0.f;
    const half8* h8 = (const half8*)(h1h + (size_t)n * F1);
#pragma unroll
    for (int i8 = 0; i8 < F1 / 8; i8++) {
        half8 hv = h8[i8];
#pragma unroll
        for (int kk = 0; kk < 8; kk++) {
            float hk = (float)hv[kk];
            int i = i8 * 8 + kk;
#pragma unroll
            for (int j = 0; j < FOUT; j++)
                acc[j] = fmaf(hk, W2[i * FOUT + j], acc[j]);   // wave-uniform -> scalar
        }
    }
    float ss = 0.f, dd = 0.f;
#pragma unroll
    for (int j = 0; j < FOUT; j++) {
        ss = fmaf(acc[j], a2s[j], ss);
        dd = fmaf(acc[j], a2d[j], dd);
    }
    half8* o8 = (half8*)(xw2h + (size_t)n * FOUT);
#pragma unroll
    for (int j8 = 0; j8 < FOUT / 8; j8++) {
        half8 o;
#pragma unroll
        for (int k = 0; k < 8; k++) o[k] = (_Float16)acc[j8 * 8 + k];
        o8[j8] = o;
    }
    as2[n] = ss;
    ad2[n] = dd;
}

// ---------------- Layer 2: gather softmax-aggregate + bias + log_softmax ----------------
// 64 lanes per node: quarters process interleaved edges, unroll x4 -> 16 in flight.

__global__ __launch_bounds__(256) void k_gather2(const int* __restrict__ rowstart, const int* __restrict__ esrc,
        const float* __restrict__ as2, const float* __restrict__ ad2,
        const _Float16* __restrict__ xw2h, const float* __restrict__ b2,
        float* __restrict__ out) {
    int n = blockIdx.x * 4 + (threadIdx.x >> 6);
    if (n >= NN) return;
    int l = threadIdx.x & 63;
    int c = l & 15;
    int q = l >> 4;
    float adn = ad2[n];
    int beg = rowstart[n], end = rowstart[n + 1];
    float accn = 0.f, accd = 0.f;
    int i = beg + q;
    for (; i + 12 < end; i += 16) {
        int s0 = esrc[i], s1 = esrc[i + 4], s2 = esrc[i + 8], s3 = esrc[i + 12];
        float e0 = as2[s0] + adn;
        float e1 = as2[s1] + adn;
        float e2 = as2[s2] + adn;
        float e3 = as2[s3] + adn;
        float x0 = (float)xw2h[s0 * FOUT + c];
        float x1 = (float)xw2h[s1 * FOUT + c];
        float x2 = (float)xw2h[s2 * FOUT + c];
        float x3 = (float)xw2h[s3 * FOUT + c];
        e0 = (e0 > 0.f) ? e0 : NSLOPE * e0;
        e1 = (e1 > 0.f) ? e1 : NSLOPE * e1;
        e2 = (e2 > 0.f) ? e2 : NSLOPE * e2;
        e3 = (e3 > 0.f) ? e3 : NSLOPE * e3;
        float ee0 = __expf(e0), ee1 = __expf(e1), ee2 = __expf(e2), ee3 = __expf(e3);
        accd += (ee0 + ee1) + (ee2 + ee3);
        accn = fmaf(ee0, x0, fmaf(ee1, x1, fmaf(ee2, x2, fmaf(ee3, x3, accn))));
    }
    for (; i < end; i += 4) {
        int s0 = esrc[i];
        float e0 = as2[s0] + adn;
        float x0 = (float)xw2h[s0 * FOUT + c];
        e0 = (e0 > 0.f) ? e0 : NSLOPE * e0;
        float ee0 = __expf(e0);
        accd += ee0;
        accn = fmaf(ee0, x0, accn);
    }
    accn += __shfl_xor(accn, 16);
    accn += __shfl_xor(accn, 32);
    accd += __shfl_xor(accd, 16);
    accd += __shfl_xor(accd, 32);
    float y = accn / accd + b2[c];
    float m = y;
#pragma unroll
    for (int off = 8; off > 0; off >>= 1) m = fmaxf(m, __shfl_xor(m, off));
    float ex = __expf(y - m);
    float sum = ex;
#pragma unroll
    for (int off = 8; off > 0; off >>= 1) sum += __shfl_xor(sum, off);
    if (l < 16) out[(size_t)n * FOUT + c] = y - m - logf(sum);
}

// ---------------- launch ----------------

extern "C" void kernel_launch(void* const* d_in, const int* in_sizes, int n_in,
                              void* d_out, int out_size, void* d_ws, size_t ws_size,
                              hipStream_t stream) {
    const float* x   = (const float*)d_in[0];
    const int*   ei  = (const int*)d_in[1];
    const float* W1  = (const float*)d_in[2];
    const float* a1s = (const float*)d_in[3];
    const float* a1d = (const float*)d_in[4];
    const float* b1  = (const float*)d_in[5];
    const float* W2  = (const float*)d_in[6];
    const float* a2s = (const float*)d_in[7];
    const float* a2d = (const float*)d_in[8];
    const float* b2  = (const float*)d_in[9];
    float* out = (float*)d_out;

    const int* srcA = ei;        // edge_index[0]
    const int* dstA = ei + NE;   // edge_index[1]

    char* w = (char*)d_ws;
    size_t off = 0;
    auto carve = [&](size_t bytes) -> void* {
        void* p = w + off;
        off = (off + bytes + 255) & ~(size_t)255;
        return p;
    };
    _Float16* xw1h = (_Float16*)carve((size_t)NN * F1 * 2);   // 6.4 MB
    float* as1     = (float*)carve((size_t)NN * H1 * 4);      // 1.6 MB
    float* ad1     = (float*)carve((size_t)NN * H1 * 4);      // 1.6 MB
    // pairs (6.8MB) aliases h1h+xw2h (9.6MB): pairs dies at k_sort, h1h/xw2h
    // are written only by later kernels (stream-ordered) -> safe.
    size_t h1_off  = off;
    _Float16* h1h  = (_Float16*)carve((size_t)NN * F1 * 2);   // 6.4 MB
    _Float16* xw2h = (_Float16*)carve((size_t)NN * FOUT * 2); // 3.2 MB
    float* as2     = (float*)carve((size_t)NN * 4);
    float* ad2     = (float*)carve((size_t)NN * 4);
    int* pairs     = (int*)(w + h1_off);                      // alias
    int* rowstart  = (int*)carve((size_t)(NN + 1) * 4);
    int* esrc      = (int*)carve((size_t)ET * 4);             // 6.8 MB
    _Float16* ew   = (_Float16*)carve((size_t)ET * H1 * 2);   // 13.6 MB (4 head planes)
    int* ptotal    = (int*)carve((size_t)NPART * CPAD * 4);   // 25 KB
    int* gcur      = (int*)carve((size_t)NPART * CPAD * 4);   // 25 KB
    int* pbase     = (int*)carve((size_t)(NPART + 1) * 4);
    (void)ws_size; (void)in_sizes; (void)n_in; (void)out_size;

    hipMemsetAsync(ptotal, 0, (size_t)NPART * CPAD * 4, stream);

    k_gemm1 <<<(NN + 255) / 256, 256, 0, stream>>>(x, W1, a1s, a1d, xw1h, as1, ad1);
    k_hist  <<<NBLK, 1024, 0, stream>>>(dstA, ptotal);
    k_pbase <<<1, 512, 0, stream>>>(ptotal, pbase, gcur, rowstart);
    k_part  <<<NBLK, 1024, 0, stream>>>(srcA, dstA, gcur, pairs);
    k_sort  <<<NPART, 1024, 0, stream>>>(pbase, pairs, as1, ad1, rowstart, esrc, ew);

    k_gather1<<<(NN + 3) / 4, 256, 0, stream>>>(rowstart, esrc, ew, xw1h, b1, h1h);
    k_node2  <<<(NN + 255) / 256, 256, 0, stream>>>(h1h, W2, a2s, a2d, xw2h, as2, ad2);
    k_gather2<<<(NN + 3) / 4, 256, 0, stream>>>(rowstart, esrc, as2, ad2, xw2h, b2, out);
}